// Round 1
// baseline (2182.329 us; speedup 1.0000x reference)
//
#include <hip/hip_runtime.h>
#include <stdint.h>

// Problem constants
#define M_DIM 4096
#define K_DIM 4096
#define N_DIM 11008
#define N_GROUPS 32   // K_DIM / 128

typedef __attribute__((ext_vector_type(8))) short short8;   // 8 bf16 bit-patterns (4 VGPRs)
typedef __attribute__((ext_vector_type(4))) float floatx4;  // MFMA accumulator

__device__ __forceinline__ unsigned short f32_to_bf16(float f) {
    unsigned int u = __float_as_uint(f);
    unsigned int rounding = 0x7FFFu + ((u >> 16) & 1u);  // RNE
    return (unsigned short)((u + rounding) >> 16);
}

// ---------------------------------------------------------------------------
// x (fp32) -> bf16 bits. Each thread converts 4 elements (float4 -> uint2).
__global__ __launch_bounds__(256) void convert_x_kernel(
    const float4* __restrict__ x, uint2* __restrict__ xb) {
    int i = blockIdx.x * 256 + threadIdx.x;
    float4 v = x[i];
    uint2 o;
    o.x = (unsigned int)f32_to_bf16(v.x) | ((unsigned int)f32_to_bf16(v.y) << 16);
    o.y = (unsigned int)f32_to_bf16(v.z) | ((unsigned int)f32_to_bf16(v.w) << 16);
    xb[i] = o;
}

// ---------------------------------------------------------------------------
// Dequant: one wave per (row, group). Lane l holds elements 2l, 2l+1 of the
// 128-element group. FWHT(128) = 1 in-lane stage (h=1) + 6 shfl_xor stages
// (h=2..64 -> lane masks 1..32). No LDS, no barriers.
__global__ __launch_bounds__(256) void dequant_kernel(
    const int* __restrict__ packed,      // [N_DIM][2048] one byte value per int
    const float* __restrict__ norms,     // [N_DIM][N_GROUPS]
    const float* __restrict__ centroids, // [16]
    const float* __restrict__ signs1,    // [128]
    const float* __restrict__ signs2,    // [128]
    unsigned int* __restrict__ w_out)    // [N_DIM][2048] two bf16 per uint
{
    const int lane = threadIdx.x & 63;
    const int wid = (blockIdx.x * 256 + threadIdx.x) >> 6;  // global wave id
    const int row = wid >> 5;        // / N_GROUPS
    const int g = wid & 31;          // % N_GROUPS
    if (row >= N_DIM) return;

    const float creg = centroids[lane & 15];
    const float2 s1 = ((const float2*)signs1)[lane];
    const float2 s2 = ((const float2*)signs2)[lane];

    unsigned int p = (unsigned int)packed[row * 2048 + g * 64 + lane];
    float v0 = __shfl(creg, (int)(p & 15u), 64);         // element 2l   (lo nibble)
    float v1 = __shfl(creg, (int)((p >> 4) & 15u), 64);  // element 2l+1 (hi nibble)

    const float scale = 0.08838834764831845f;  // 1/sqrt(128)

    // FWHT #1
    { float a = v0 + v1, b = v0 - v1; v0 = a; v1 = b; }
#pragma unroll
    for (int m = 1; m <= 32; m <<= 1) {
        float o0 = __shfl_xor(v0, m, 64);
        float o1 = __shfl_xor(v1, m, 64);
        bool up = (lane & m) != 0;
        v0 = up ? o0 - v0 : v0 + o0;
        v1 = up ? o1 - v1 : v1 + o1;
    }
    v0 *= scale * s2.x;
    v1 *= scale * s2.y;

    // FWHT #2
    { float a = v0 + v1, b = v0 - v1; v0 = a; v1 = b; }
#pragma unroll
    for (int m = 1; m <= 32; m <<= 1) {
        float o0 = __shfl_xor(v0, m, 64);
        float o1 = __shfl_xor(v1, m, 64);
        bool up = (lane & m) != 0;
        v0 = up ? o0 - v0 : v0 + o0;
        v1 = up ? o1 - v1 : v1 + o1;
    }
    float nrm = norms[row * N_GROUPS + g] * scale;
    v0 *= nrm * s1.x;
    v1 *= nrm * s1.y;

    w_out[row * 2048 + g * 64 + lane] =
        (unsigned int)f32_to_bf16(v0) | ((unsigned int)f32_to_bf16(v1) << 16);
}

// ---------------------------------------------------------------------------
// GEMM: C[M][N] = A[M][K] * B[N][K]^T + bias.  A = x bf16, B = w bf16 (row-major N x K).
// 128x128 tile, BK=64, 4 waves in 2x2, each wave 64x64 via 4x4 mfma 16x16x32.
#define BM 128
#define BN 128
#define BK 64

__global__ __launch_bounds__(256) void gemm_bt_kernel(
    const unsigned short* __restrict__ A,   // [M_DIM][K_DIM] bf16 bits
    const unsigned short* __restrict__ B,   // [N_DIM][K_DIM] bf16 bits
    const float* __restrict__ bias,         // [N_DIM]
    float* __restrict__ C)                  // [M_DIM][N_DIM]
{
    __shared__ __align__(16) short As[BM * BK];
    __shared__ __align__(16) short Bs[BN * BK];

    const int tid = threadIdx.x;
    const int wave = tid >> 6, lane = tid & 63;
    const int wm = wave >> 1, wn = wave & 1;
    const int col16 = lane & 15, quad = lane >> 4;
    const int m0 = blockIdx.y * BM, n0 = blockIdx.x * BN;

    floatx4 acc[4][4] = {};

    uint4 ra[4], rb[4];

    auto load_tiles = [&](int kt) {
#pragma unroll
        for (int i = 0; i < 4; ++i) {
            int c = tid + 256 * i;         // chunk 0..1023; 8 chunks (of 8 bf16) per row
            int row = c >> 3, kc = c & 7;
            ra[i] = *(const uint4*)(A + (size_t)(m0 + row) * K_DIM + kt * BK + kc * 8);
            rb[i] = *(const uint4*)(B + (size_t)(n0 + row) * K_DIM + kt * BK + kc * 8);
        }
    };

    const int nk = K_DIM / BK;
    load_tiles(0);

    for (int kt = 0; kt < nk; ++kt) {
        __syncthreads();
#pragma unroll
        for (int i = 0; i < 4; ++i) {
            int c = tid + 256 * i;
            int row = c >> 3, kc = c & 7;
            *(uint4*)(As + row * BK + kc * 8) = ra[i];
            *(uint4*)(Bs + row * BK + kc * 8) = rb[i];
        }
        __syncthreads();
        if (kt + 1 < nk) load_tiles(kt + 1);

#pragma unroll
        for (int ks = 0; ks < BK / 32; ++ks) {
            short8 af[4], bf[4];
#pragma unroll
            for (int mi = 0; mi < 4; ++mi) {
                af[mi] = *(const short8*)(As + (wm * 64 + mi * 16 + col16) * BK + ks * 32 + quad * 8);
                bf[mi] = *(const short8*)(Bs + (wn * 64 + mi * 16 + col16) * BK + ks * 32 + quad * 8);
            }
#pragma unroll
            for (int mi = 0; mi < 4; ++mi)
#pragma unroll
                for (int ni = 0; ni < 4; ++ni)
                    acc[mi][ni] = __builtin_amdgcn_mfma_f32_16x16x32_bf16(
                        af[mi], bf[ni], acc[mi][ni], 0, 0, 0);
        }
    }

    // Epilogue: C/D layout col=lane&15, row=quad*4+reg
#pragma unroll
    for (int ni = 0; ni < 4; ++ni) {
        int gcol = n0 + wn * 64 + ni * 16 + col16;
        float bv = bias[gcol];
#pragma unroll
        for (int mi = 0; mi < 4; ++mi) {
            int grow = m0 + wm * 64 + mi * 16 + quad * 4;
#pragma unroll
            for (int r = 0; r < 4; ++r) {
                C[(size_t)(grow + r) * N_DIM + gcol] = acc[mi][ni][r] + bv;
            }
        }
    }
}

// ---------------------------------------------------------------------------
extern "C" void kernel_launch(void* const* d_in, const int* in_sizes, int n_in,
                              void* d_out, int out_size, void* d_ws, size_t ws_size,
                              hipStream_t stream) {
    const float* x        = (const float*)d_in[0];  // [4096][4096]
    const int* packed     = (const int*)d_in[1];    // [11008][2048]
    const float* norms    = (const float*)d_in[2];  // [11008][32]
    const float* centroids= (const float*)d_in[3];  // [16]
    const float* signs1   = (const float*)d_in[4];  // [128]
    const float* signs2   = (const float*)d_in[5];  // [128]
    const float* bias     = (const float*)d_in[6];  // [11008]
    float* out            = (float*)d_out;          // [4096][11008]

    // Workspace: w_bf16 (11008*4096*2 B = 90.2 MB) then x_bf16 (33.6 MB)
    unsigned short* w_bf16 = (unsigned short*)d_ws;
    unsigned short* x_bf16 = (unsigned short*)((char*)d_ws + (size_t)N_DIM * K_DIM * 2);

    // 1) x -> bf16
    convert_x_kernel<<<(M_DIM * K_DIM) / 4 / 256, 256, 0, stream>>>(
        (const float4*)x, (uint2*)x_bf16);

    // 2) dequantize weights -> bf16 (one wave per row-group; 11008*32 waves)
    dequant_kernel<<<(N_DIM * N_GROUPS) / 4, 256, 0, stream>>>(
        packed, norms, centroids, signs1, signs2, (unsigned int*)w_bf16);

    // 3) GEMM + bias
    gemm_bt_kernel<<<dim3(N_DIM / BN, M_DIM / BM), 256, 0, stream>>>(
        x_bf16, w_bf16, bias, out);
}

// Round 2
// 761.098 us; speedup vs baseline: 2.8673x; 2.8673x over previous
//
#include <hip/hip_runtime.h>
#include <stdint.h>

// Problem constants
#define M_DIM 4096
#define K_DIM 4096
#define N_DIM 11008
#define N_GROUPS 32   // K_DIM / 128

typedef __attribute__((ext_vector_type(8))) short short8;   // 8 bf16 bit-patterns (4 VGPRs)
typedef __attribute__((ext_vector_type(4))) float floatx4;  // MFMA accumulator

__device__ __forceinline__ unsigned short f32_to_bf16(float f) {
    unsigned int u = __float_as_uint(f);
    unsigned int rounding = 0x7FFFu + ((u >> 16) & 1u);  // RNE
    return (unsigned short)((u + rounding) >> 16);
}

// ---------------------------------------------------------------------------
// x (fp32) -> bf16 bits. Each thread converts 4 elements (float4 -> uint2).
__global__ __launch_bounds__(256) void convert_x_kernel(
    const float4* __restrict__ x, uint2* __restrict__ xb) {
    int i = blockIdx.x * 256 + threadIdx.x;
    float4 v = x[i];
    uint2 o;
    o.x = (unsigned int)f32_to_bf16(v.x) | ((unsigned int)f32_to_bf16(v.y) << 16);
    o.y = (unsigned int)f32_to_bf16(v.z) | ((unsigned int)f32_to_bf16(v.w) << 16);
    xb[i] = o;
}

// ---------------------------------------------------------------------------
// Dequant: one wave per (row, group). Lane l holds elements 2l, 2l+1 of the
// 128-element group. FWHT(128) = 1 in-lane stage + 6 shfl_xor stages.
__global__ __launch_bounds__(256) void dequant_kernel(
    const int* __restrict__ packed,      // [N_DIM][2048] one byte value per int
    const float* __restrict__ norms,     // [N_DIM][N_GROUPS]
    const float* __restrict__ centroids, // [16]
    const float* __restrict__ signs1,    // [128]
    const float* __restrict__ signs2,    // [128]
    unsigned int* __restrict__ w_out)    // [N_DIM][2048] two bf16 per uint
{
    const int lane = threadIdx.x & 63;
    const int wid = (blockIdx.x * 256 + threadIdx.x) >> 6;  // global wave id
    const int row = wid >> 5;        // / N_GROUPS
    const int g = wid & 31;          // % N_GROUPS
    if (row >= N_DIM) return;

    const float creg = centroids[lane & 15];
    const float2 s1 = ((const float2*)signs1)[lane];
    const float2 s2 = ((const float2*)signs2)[lane];

    unsigned int p = (unsigned int)packed[row * 2048 + g * 64 + lane];
    float v0 = __shfl(creg, (int)(p & 15u), 64);         // element 2l   (lo nibble)
    float v1 = __shfl(creg, (int)((p >> 4) & 15u), 64);  // element 2l+1 (hi nibble)

    const float scale = 0.08838834764831845f;  // 1/sqrt(128)

    // FWHT #1
    { float a = v0 + v1, b = v0 - v1; v0 = a; v1 = b; }
#pragma unroll
    for (int m = 1; m <= 32; m <<= 1) {
        float o0 = __shfl_xor(v0, m, 64);
        float o1 = __shfl_xor(v1, m, 64);
        bool up = (lane & m) != 0;
        v0 = up ? o0 - v0 : v0 + o0;
        v1 = up ? o1 - v1 : v1 + o1;
    }
    v0 *= scale * s2.x;
    v1 *= scale * s2.y;

    // FWHT #2
    { float a = v0 + v1, b = v0 - v1; v0 = a; v1 = b; }
#pragma unroll
    for (int m = 1; m <= 32; m <<= 1) {
        float o0 = __shfl_xor(v0, m, 64);
        float o1 = __shfl_xor(v1, m, 64);
        bool up = (lane & m) != 0;
        v0 = up ? o0 - v0 : v0 + o0;
        v1 = up ? o1 - v1 : v1 + o1;
    }
    float nrm = norms[row * N_GROUPS + g] * scale;
    v0 *= nrm * s1.x;
    v1 *= nrm * s1.y;

    w_out[row * 2048 + g * 64 + lane] =
        (unsigned int)f32_to_bf16(v0) | ((unsigned int)f32_to_bf16(v1) << 16);
}

// ---------------------------------------------------------------------------
// GEMM: C[M][N] = A[M][K] * B[N][K]^T + bias. m97-style: global_load_lds
// width-16 staging with XOR chunk swizzle; coalesced LDS-staged epilogue.
#define BM 128
#define BN 128
#define BK 64
#define SMEM_BYTES 33792   // max(As+Bs = 32768, Cs = 64*132*4 = 33792)

typedef const __attribute__((address_space(1))) void* gvp_t;
typedef __attribute__((address_space(3))) void* svp_t;

__global__ __launch_bounds__(256, 4) void gemm_bt_kernel(
    const unsigned short* __restrict__ A,   // [M_DIM][K_DIM] bf16 bits
    const unsigned short* __restrict__ B,   // [N_DIM][K_DIM] bf16 bits
    const float* __restrict__ bias,         // [N_DIM]
    float* __restrict__ C)                  // [M_DIM][N_DIM]
{
    __shared__ __align__(16) char smem[SMEM_BYTES];
    short* AsS = (short*)smem;              // 128 rows x 64 bf16 = 16 KB
    short* BsS = (short*)(smem + 16384);    // 16 KB

    const int tid = threadIdx.x;
    const int wave = tid >> 6, lane = tid & 63;
    const int wm = wave >> 1, wn = wave & 1;
    const int col16 = lane & 15, quad = lane >> 4;

    // M-panel swizzle: 4 panels of 8 M-tiles, sweep all 86 N-tiles per panel.
    // Keeps B (90 MB) + A-panel (8 MB) L3-resident.
    int id = blockIdx.x;
    int panel = id / 688;            // 688 = 86 * 8
    int rem = id - panel * 688;
    int nt = rem >> 3;               // 0..85
    int mt = panel * 8 + (rem & 7);  // 0..31
    const int m0 = mt * BM, n0 = nt * BN;

    // Staging geometry: tile = 128 rows x 8 chunks (16 B each). Wave w, iter i,
    // lane l stages LDS chunk lc = (w*4+i)*64 + l  -> (row = lc>>3, c = lc&7).
    // XOR swizzle on SOURCE: global chunk gc = c ^ (row & 7); row&7 == l>>3.
    const int srow = (lane >> 3);                    // 0..7 within 8-row slab
    const int gc = (lane & 7) ^ srow;                // swizzled source chunk
    const unsigned short* aPtr = A + (size_t)(m0 + wave * 32 + srow) * K_DIM + gc * 8;
    const unsigned short* bPtr = B + (size_t)(n0 + wave * 32 + srow) * K_DIM + gc * 8;

    floatx4 acc[4][4] = {};

    const int nk = K_DIM / BK;  // 64
    for (int kt = 0; kt < nk; ++kt) {
        __syncthreads();   // all waves done reading previous tile
#pragma unroll
        for (int i = 0; i < 4; ++i) {
            __builtin_amdgcn_global_load_lds(
                (gvp_t)(aPtr + (size_t)i * 8 * K_DIM + kt * BK),
                (svp_t)(AsS + (wave * 4 + i) * 512), 16, 0, 0);
            __builtin_amdgcn_global_load_lds(
                (gvp_t)(bPtr + (size_t)i * 8 * K_DIM + kt * BK),
                (svp_t)(BsS + (wave * 4 + i) * 512), 16, 0, 0);
        }
        __syncthreads();   // vmcnt drained before barrier -> LDS tile visible

#pragma unroll
        for (int ks = 0; ks < BK / 32; ++ks) {
            // fragment chunk (swizzled): cl = (ks*4+quad) ^ (row&7); row&7 == col16&7
            const int cl = ((ks * 4 + quad) ^ (col16 & 7)) * 8;
            short8 af[4], bf[4];
#pragma unroll
            for (int mi = 0; mi < 4; ++mi) {
                af[mi] = *(const short8*)(AsS + (wm * 64 + mi * 16 + col16) * BK + cl);
                bf[mi] = *(const short8*)(BsS + (wn * 64 + mi * 16 + col16) * BK + cl);
            }
#pragma unroll
            for (int mi = 0; mi < 4; ++mi)
#pragma unroll
                for (int ni = 0; ni < 4; ++ni)
                    acc[mi][ni] = __builtin_amdgcn_mfma_f32_16x16x32_bf16(
                        af[mi], bf[ni], acc[mi][ni], 0, 0, 0);
        }
    }

    // ---------------- Epilogue: LDS-staged, full-line coalesced stores ------
    // C/D layout: col = lane&15, row = quad*4 + reg.
    float bv[4];
#pragma unroll
    for (int ni = 0; ni < 4; ++ni) bv[ni] = bias[n0 + wn * 64 + ni * 16 + col16];

    float* Cs = (float*)smem;   // 64 rows x 132 stride (padded) fp32
#pragma unroll
    for (int s = 0; s < 2; ++s) {
        __syncthreads();        // previous slab reads (or K-loop LDS reads) done
        if (wm == s) {
#pragma unroll
            for (int mi = 0; mi < 4; ++mi)
#pragma unroll
                for (int ni = 0; ni < 4; ++ni)
#pragma unroll
                    for (int r = 0; r < 4; ++r)
                        Cs[(mi * 16 + quad * 4 + r) * 132 + wn * 64 + ni * 16 + col16] =
                            acc[mi][ni][r] + bv[ni];
        }
        __syncthreads();
        // 256 threads stream 64 rows x 128 cols: 512 B contiguous per row
#pragma unroll
        for (int p = 0; p < 8; ++p) {
            int rr = p * 8 + (tid >> 5);
            int c4 = (tid & 31) * 4;
            float4 v = *(const float4*)(Cs + rr * 132 + c4);
            *(float4*)(C + (size_t)(m0 + s * 64 + rr) * N_DIM + n0 + c4) = v;
        }
    }
}

// ---------------------------------------------------------------------------
extern "C" void kernel_launch(void* const* d_in, const int* in_sizes, int n_in,
                              void* d_out, int out_size, void* d_ws, size_t ws_size,
                              hipStream_t stream) {
    const float* x        = (const float*)d_in[0];  // [4096][4096]
    const int* packed     = (const int*)d_in[1];    // [11008][2048]
    const float* norms    = (const float*)d_in[2];  // [11008][32]
    const float* centroids= (const float*)d_in[3];  // [16]
    const float* signs1   = (const float*)d_in[4];  // [128]
    const float* signs2   = (const float*)d_in[5];  // [128]
    const float* bias     = (const float*)d_in[6];  // [11008]
    float* out            = (float*)d_out;          // [4096][11008]

    // Workspace: w_bf16 (90.2 MB) then x_bf16 (33.6 MB)
    unsigned short* w_bf16 = (unsigned short*)d_ws;
    unsigned short* x_bf16 = (unsigned short*)((char*)d_ws + (size_t)N_DIM * K_DIM * 2);

    convert_x_kernel<<<(M_DIM * K_DIM) / 4 / 256, 256, 0, stream>>>(
        (const float4*)x, (uint2*)x_bf16);

    dequant_kernel<<<(N_DIM * N_GROUPS) / 4, 256, 0, stream>>>(
        packed, norms, centroids, signs1, signs2, (unsigned int*)w_bf16);

    gemm_bt_kernel<<<dim3((N_DIM / BN) * (M_DIM / BM)), 256, 0, stream>>>(
        x_bf16, w_bf16, bias, out);
}

// Round 4
// 715.920 us; speedup vs baseline: 3.0483x; 1.0631x over previous
//
#include <hip/hip_runtime.h>
#include <stdint.h>

// Problem constants
#define M_DIM 4096
#define K_DIM 4096
#define N_DIM 11008
#define N_GROUPS 32   // K_DIM / 128

typedef __attribute__((ext_vector_type(8))) short short8;   // 8 bf16 bit-patterns (4 VGPRs)
typedef __attribute__((ext_vector_type(4))) float floatx4;  // MFMA accumulator / NT store

__device__ __forceinline__ unsigned short f32_to_bf16(float f) {
    unsigned int u = __float_as_uint(f);
    unsigned int rounding = 0x7FFFu + ((u >> 16) & 1u);  // RNE
    return (unsigned short)((u + rounding) >> 16);
}

// ---------------------------------------------------------------------------
// Mt[i][j] = M[j][i] where M = H*diag(s2)*H*diag(s1) applied to x:
// z_i = sum_j M^T[i,j] x_j ; Mt[i][j] = s1[j]/128 * sum_a (-1)^(popc(i&a)+popc(a&j)) s2[a]
__global__ __launch_bounds__(128) void make_M_kernel(
    const float* __restrict__ signs1, const float* __restrict__ signs2,
    unsigned short* __restrict__ Mt)   // [128][128] bf16
{
    const int i = blockIdx.x;    // z-column
    const int j = threadIdx.x;   // x-row
    __shared__ float s2s[128];
    s2s[j] = signs2[j];
    __syncthreads();
    float acc = 0.f;
#pragma unroll 8
    for (int a = 0; a < 128; ++a) {
        int par = (__popc(i & a) + __popc(a & j)) & 1;
        acc += par ? -s2s[a] : s2s[a];
    }
    Mt[i * 128 + j] = f32_to_bf16(signs1[j] * acc * (1.0f / 128.0f));
}

// ---------------------------------------------------------------------------
// Z = X * M per 128-group (block-diagonal). One block: 64 rows x 1 group.
// Fuses fp32->bf16 conversion of x. MFMA 16x16x32, K=128.
#define TX_RS 136   // padded LDS row stride (shorts)

__global__ __launch_bounds__(256) void transform_x_kernel(
    const float* __restrict__ x,            // [M_DIM][K_DIM] fp32
    const unsigned short* __restrict__ Mt,  // [128][128] bf16
    unsigned short* __restrict__ z)         // [M_DIM][K_DIM] bf16
{
    __shared__ __align__(16) short Xs[64 * TX_RS];
    __shared__ __align__(16) short Ms[128 * TX_RS];

    const int tid = threadIdx.x;
    const int wave = tid >> 6, lane = tid & 63;
    const int col16 = lane & 15, quad = lane >> 4;
    const int m0 = (blockIdx.x >> 5) * 64;
    const int g = blockIdx.x & 31;
    const int c0 = g * 128;

    // stage X tile (64 x 128 fp32 -> bf16)
#pragma unroll
    for (int it = 0; it < 8; ++it) {
        int idx = tid + 256 * it;            // 2048 float4 chunks
        int row = idx >> 5, c4 = idx & 31;
        float4 v = *(const float4*)(x + (size_t)(m0 + row) * K_DIM + c0 + c4 * 4);
        uint2 o;
        o.x = (unsigned)f32_to_bf16(v.x) | ((unsigned)f32_to_bf16(v.y) << 16);
        o.y = (unsigned)f32_to_bf16(v.z) | ((unsigned)f32_to_bf16(v.w) << 16);
        *(uint2*)(Xs + row * TX_RS + c4 * 4) = o;
    }
    // stage Mt (128 x 128 bf16)
#pragma unroll
    for (int it = 0; it < 8; ++it) {
        int ch = tid + 256 * it;             // 2048 chunks of 8 shorts
        int row = ch >> 4, cc = ch & 15;
        uint4 v = *(const uint4*)(Mt + (size_t)ch * 8);
        *(uint4*)(Ms + row * TX_RS + cc * 8) = v;
    }
    __syncthreads();

    floatx4 acc[8] = {};
#pragma unroll
    for (int ks = 0; ks < 4; ++ks) {
        short8 af = *(const short8*)(Xs + (wave * 16 + col16) * TX_RS + ks * 32 + quad * 8);
#pragma unroll
        for (int ni = 0; ni < 8; ++ni) {
            short8 bf = *(const short8*)(Ms + (ni * 16 + col16) * TX_RS + ks * 32 + quad * 8);
            acc[ni] = __builtin_amdgcn_mfma_f32_16x16x32_bf16(af, bf, acc[ni], 0, 0, 0);
        }
    }
    // write z (C/D layout: col=lane&15, row=quad*4+r)
#pragma unroll
    for (int ni = 0; ni < 8; ++ni)
#pragma unroll
        for (int r = 0; r < 4; ++r) {
            int row = m0 + wave * 16 + quad * 4 + r;
            z[(size_t)row * K_DIM + c0 + ni * 16 + col16] = f32_to_bf16(acc[ni][r]);
        }
}

// ---------------------------------------------------------------------------
// Dequant is now a pure LUT: w'[n, g*128+j] = norms[n,g] * centroids[idx].
// One block per output row (2048 ints = 4096 elems). 8 ints/thread.
__global__ __launch_bounds__(256) void dequant_lut_kernel(
    const int* __restrict__ packed,      // [N_DIM][2048]
    const float* __restrict__ norms,     // [N_DIM][N_GROUPS]
    const float* __restrict__ centroids, // [16]
    unsigned int* __restrict__ w_out)    // [N_DIM][2048] two bf16 per uint
{
    __shared__ float2 lut[256];
    const int tid = threadIdx.x;
    lut[tid] = make_float2(centroids[tid & 15], centroids[tid >> 4]);
    __syncthreads();

    const int row = blockIdx.x;
    const int g = tid >> 3;                 // 8 threads per 64-int group
    const float nrm = norms[row * N_GROUPS + g];
    const int* prow = packed + (size_t)row * 2048 + tid * 8;
    int4 pa = *(const int4*)(prow);
    int4 pb = *(const int4*)(prow + 4);
    int v[8] = {pa.x, pa.y, pa.z, pa.w, pb.x, pb.y, pb.z, pb.w};
    unsigned o[8];
#pragma unroll
    for (int q = 0; q < 8; ++q) {
        float2 c = lut[v[q] & 255];
        o[q] = (unsigned)f32_to_bf16(c.x * nrm) | ((unsigned)f32_to_bf16(c.y * nrm) << 16);
    }
    unsigned* orow = w_out + (size_t)row * 2048 + tid * 8;
    *(uint4*)(orow)     = make_uint4(o[0], o[1], o[2], o[3]);
    *(uint4*)(orow + 4) = make_uint4(o[4], o[5], o[6], o[7]);
}

// ---------------------------------------------------------------------------
// GEMM: C[M][N] = Z[M][K] * W[N][K]^T + bias. m97-style global_load_lds
// staging with XOR chunk swizzle; LDS-staged coalesced NT-store epilogue.
#define BM 128
#define BN 128
#define BK 64
#define SMEM_BYTES 33792   // max(As+Bs = 32768, Cs = 64*132*4 = 33792)

typedef const __attribute__((address_space(1))) void* gvp_t;
typedef __attribute__((address_space(3))) void* svp_t;

__global__ __launch_bounds__(256, 4) void gemm_bt_kernel(
    const unsigned short* __restrict__ A,   // [M_DIM][K_DIM] bf16 bits (= Z)
    const unsigned short* __restrict__ B,   // [N_DIM][K_DIM] bf16 bits (= W')
    const float* __restrict__ bias,         // [N_DIM]
    float* __restrict__ C)                  // [M_DIM][N_DIM]
{
    __shared__ __align__(16) char smem[SMEM_BYTES];
    short* AsS = (short*)smem;              // 128 rows x 64 bf16 = 16 KB
    short* BsS = (short*)(smem + 16384);    // 16 KB

    const int tid = threadIdx.x;
    const int wave = tid >> 6, lane = tid & 63;
    const int wm = wave >> 1, wn = wave & 1;
    const int col16 = lane & 15, quad = lane >> 4;

    // M-panel swizzle: 4 panels of 8 M-tiles, sweep all 86 N-tiles per panel.
    int id = blockIdx.x;
    int panel = id / 688;            // 688 = 86 * 8
    int rem = id - panel * 688;
    int nt = rem >> 3;               // 0..85
    int mt = panel * 8 + (rem & 7);  // 0..31
    const int m0 = mt * BM, n0 = nt * BN;

    // Staging: tile = 128 rows x 8 chunks (16 B). XOR swizzle on SOURCE chunk.
    const int srow = (lane >> 3);
    const int gc = (lane & 7) ^ srow;
    const unsigned short* aPtr = A + (size_t)(m0 + wave * 32 + srow) * K_DIM + gc * 8;
    const unsigned short* bPtr = B + (size_t)(n0 + wave * 32 + srow) * K_DIM + gc * 8;

    floatx4 acc[4][4] = {};

    const int nk = K_DIM / BK;  // 64
    for (int kt = 0; kt < nk; ++kt) {
        __syncthreads();
#pragma unroll
        for (int i = 0; i < 4; ++i) {
            __builtin_amdgcn_global_load_lds(
                (gvp_t)(aPtr + (size_t)i * 8 * K_DIM + kt * BK),
                (svp_t)(AsS + (wave * 4 + i) * 512), 16, 0, 0);
            __builtin_amdgcn_global_load_lds(
                (gvp_t)(bPtr + (size_t)i * 8 * K_DIM + kt * BK),
                (svp_t)(BsS + (wave * 4 + i) * 512), 16, 0, 0);
        }
        __syncthreads();

#pragma unroll
        for (int ks = 0; ks < BK / 32; ++ks) {
            const int cl = ((ks * 4 + quad) ^ (col16 & 7)) * 8;
            short8 af[4], bf[4];
#pragma unroll
            for (int mi = 0; mi < 4; ++mi) {
                af[mi] = *(const short8*)(AsS + (wm * 64 + mi * 16 + col16) * BK + cl);
                bf[mi] = *(const short8*)(BsS + (wn * 64 + mi * 16 + col16) * BK + cl);
            }
#pragma unroll
            for (int mi = 0; mi < 4; ++mi)
#pragma unroll
                for (int ni = 0; ni < 4; ++ni)
                    acc[mi][ni] = __builtin_amdgcn_mfma_f32_16x16x32_bf16(
                        af[mi], bf[ni], acc[mi][ni], 0, 0, 0);
        }
    }

    // Epilogue: LDS-staged, full-line coalesced NT stores
    float bv[4];
#pragma unroll
    for (int ni = 0; ni < 4; ++ni) bv[ni] = bias[n0 + wn * 64 + ni * 16 + col16];

    float* Cs = (float*)smem;   // 64 rows x 132 stride fp32
#pragma unroll
    for (int s = 0; s < 2; ++s) {
        __syncthreads();
        if (wm == s) {
#pragma unroll
            for (int mi = 0; mi < 4; ++mi)
#pragma unroll
                for (int ni = 0; ni < 4; ++ni)
#pragma unroll
                    for (int r = 0; r < 4; ++r)
                        Cs[(mi * 16 + quad * 4 + r) * 132 + wn * 64 + ni * 16 + col16] =
                            acc[mi][ni][r] + bv[ni];
        }
        __syncthreads();
#pragma unroll
        for (int p = 0; p < 8; ++p) {
            int rr = p * 8 + (tid >> 5);
            int c4 = (tid & 31) * 4;
            floatx4 v = *(const floatx4*)(Cs + rr * 132 + c4);
            __builtin_nontemporal_store(v,
                (floatx4*)(C + (size_t)(m0 + s * 64 + rr) * N_DIM + n0 + c4));
        }
    }
}

// ---------------------------------------------------------------------------
extern "C" void kernel_launch(void* const* d_in, const int* in_sizes, int n_in,
                              void* d_out, int out_size, void* d_ws, size_t ws_size,
                              hipStream_t stream) {
    const float* x        = (const float*)d_in[0];  // [4096][4096]
    const int* packed     = (const int*)d_in[1];    // [11008][2048]
    const float* norms    = (const float*)d_in[2];  // [11008][32]
    const float* centroids= (const float*)d_in[3];  // [16]
    const float* signs1   = (const float*)d_in[4];  // [128]
    const float* signs2   = (const float*)d_in[5];  // [128]
    const float* bias     = (const float*)d_in[6];  // [11008]
    float* out            = (float*)d_out;          // [4096][11008]

    // Workspace: Mt (32 KB) | w_bf16 (90.2 MB) | z_bf16 (33.6 MB)
    unsigned short* Mt     = (unsigned short*)d_ws;
    unsigned short* w_bf16 = (unsigned short*)((char*)d_ws + 32768);
    unsigned short* z_bf16 = (unsigned short*)((char*)d_ws + 32768 + (size_t)N_DIM * K_DIM * 2);

    make_M_kernel<<<128, 128, 0, stream>>>(signs1, signs2, Mt);

    transform_x_kernel<<<(M_DIM / 64) * N_GROUPS, 256, 0, stream>>>(x, Mt, z_bf16);

    dequant_lut_kernel<<<N_DIM, 256, 0, stream>>>(
        packed, norms, centroids, (unsigned int*)w_bf16);

    gemm_bt_kernel<<<dim3((N_DIM / BN) * (M_DIM / BM)), 256, 0, stream>>>(
        z_bf16, w_bf16, bias, out);
}